// Round 13
// baseline (280.073 us; speedup 1.0000x reference)
//
#include <hip/hip_runtime.h>
#include <hip/hip_fp16.h>
#include <math.h>

#define IN_F 512
#define C_DIM 16
#define CP 17        // C + 1 (extra attention column)
#define MPAD 20      // padded row stride for combined matrices (16B-aligned)
#define EF_DIM 64
#define BSHIFT 6     // nodes-per-bucket shift
#define NPB 64       // nodes per bucket; local id fits in 6 bits
#define NBMAX2 2048  // max buckets (N <= 131072: tail fits 17 bits)
#define CNTW 2048    // cnt table row width
#define SCB 512      // scatter/hist partition blocks
#define CAP 2560     // per-bucket sorted-record capacity
// record: { local(6)[17:22] | tail(17)[0:16] , float ex }

typedef float f32x4 __attribute__((ext_vector_type(4)));
typedef unsigned u32x2 __attribute__((ext_vector_type(2)));
typedef unsigned u32x4 __attribute__((ext_vector_type(4)));
typedef _Float16 f16x4 __attribute__((ext_vector_type(4)));
typedef _Float16 f16x8 __attribute__((ext_vector_type(8)));

union U2H { unsigned u; __half2 h; };

// ---------------------------------------------------------------------------
// K0: prep. Combined f32 matrices, 8-entry edge-type table, and
// fragment-packed f16 B matrices for the MFMA proj (layout per R12).
// ---------------------------------------------------------------------------
__global__ __launch_bounds__(512) void prep_kernel(
    const float* __restrict__ W, const float* __restrict__ We,
    const float* __restrict__ al, const float* __restrict__ ar,
    const float* __restrict__ ae, const float* __restrict__ emb,
    const float* __restrict__ resW,
    float* __restrict__ Wh, float* __restrict__ Wt, float* __restrict__ he,
    _Float16* __restrict__ Bph, _Float16* __restrict__ Bpt, int NET) {
  __shared__ float v[EF_DIM];
  int t = threadIdx.x;  // 0..511 == k index for phase 1
  float wl = 0.f, wr = 0.f;
#pragma unroll
  for (int c = 0; c < C_DIM; c++) {
    float wv = W[t * C_DIM + c];
    wl += wv * al[c];
    wr += wv * ar[c];
    Wt[t * MPAD + c] = wv;
    Wh[t * MPAD + c] = resW[t * C_DIM + c];
  }
  Wh[t * MPAD + C_DIM] = wl;
  Wt[t * MPAD + C_DIM] = wr;
  if (t < EF_DIM) {
    float s = 0.f;
    for (int f = 0; f < EF_DIM; f++) s += We[t * EF_DIM + f] * ae[f];
    v[t] = s;
  }
  __syncthreads();
  if (t < NET) {
    float s = 0.f;
    for (int k = 0; k < EF_DIM; k++) s += emb[t * EF_DIM + k] * v[k];
    he[t] = s;
  }
  // phase 2: MFMA B fragments (16384 f16 per matrix)
  for (int i = 0; i < 32; i++) {
    int flat = t + 512 * i;
    int j = flat & 7;
    int l = (flat >> 3) & 63;
    int n = (flat >> 9) & 1;
    int s = flat >> 10;  // 0..15
    int k = 32 * s + ((l >> 4) << 3) + j;
    int c = (l & 15) + 16 * n;
    float bh = 0.f, bt = 0.f;
    if (c < C_DIM) {
      bh = resW[k * C_DIM + c];
      bt = W[k * C_DIM + c];
    } else if (c == C_DIM) {
      for (int cc = 0; cc < C_DIM; cc++) {
        float wv = W[k * C_DIM + cc];
        bh += wv * al[cc];
        bt += wv * ar[cc];
      }
    }
    Bph[flat] = (_Float16)bh;
    Bpt[flat] = (_Float16)bt;
  }
}

// ---------------------------------------------------------------------------
// K1: proj5 v2 -- MFMA GEMM with DOUBLE-BUFFERED staging (T14):
// per chunk, issue chunk k+1's global loads into regs BEFORE the MFMA
// phase on chunk k; convert + ds_write after; ONE barrier per iteration
// (write targets the opposite LDS buffer, so the post-MFMA barrier is
// unnecessary: MFMA(kc) reads As[kc&1], write goes to As[(kc+1)&1]).
// R12's schedule exposed the full ~900cy load latency serially (5
// structures all ~135us, all pipes <20%); this overlaps it with compute.
// ---------------------------------------------------------------------------
__global__ __launch_bounds__(256) void proj5_kernel(
    const float* __restrict__ hf, const float* __restrict__ tf,
    const _Float16* __restrict__ Bph, const _Float16* __restrict__ Bpt,
    float* __restrict__ resid, float* __restrict__ hl,
    __half* __restrict__ ht_, float* __restrict__ hr, int N) {
  __shared__ _Float16 As[2][64][72];
  int t = threadIdx.x;
  int w = t >> 6;
  int lane = t & 63;
  int r0 = blockIdx.x * 64;
  const float* feat = blockIdx.y ? tf : hf;     // blockIdx-uniform (R11)
  const _Float16* Bp = blockIdx.y ? Bpt : Bph;
  f32x4 acc0 = {0.f, 0.f, 0.f, 0.f};
  f32x4 acc1 = {0.f, 0.f, 0.f, 0.f};
  const int srow = t >> 4;        // staging: 16 threads per row
  const int scol = (t & 15) * 4;  // 256B contiguous per row
  const float* gp[4];
#pragma unroll
  for (int g = 0; g < 4; g++) {
    int gr = min(r0 + g * 16 + srow, N - 1);  // clamp once, outside loop
    gp[g] = feat + (size_t)gr * IN_F + scol;
  }
  f32x4 st[4];
  // prologue: stage chunk 0
#pragma unroll
  for (int g = 0; g < 4; g++) st[g] = *(const f32x4*)(gp[g]);
#pragma unroll
  for (int g = 0; g < 4; g++) {
    f16x4 hv = {(_Float16)st[g].x, (_Float16)st[g].y, (_Float16)st[g].z,
                (_Float16)st[g].w};
    *(f16x4*)(&As[0][g * 16 + srow][scol]) = hv;
  }
  __syncthreads();
  const _Float16* aptr0 = &As[0][w * 16 + (lane & 15)][(lane >> 4) * 8];
  const _Float16* aptr1 = &As[1][w * 16 + (lane & 15)][(lane >> 4) * 8];
#pragma unroll
  for (int kc = 0; kc < 8; kc++) {
    if (kc < 7) {
#pragma unroll
      for (int g = 0; g < 4; g++)
        st[g] = *(const f32x4*)(gp[g] + (kc + 1) * 64);  // issue early
    }
    const _Float16* ap = (kc & 1) ? aptr1 : aptr0;
#pragma unroll
    for (int s2 = 0; s2 < 2; s2++) {
      int s = kc * 2 + s2;
      f16x8 a = *(const f16x8*)(ap + s2 * 32);
      f16x8 b0 = *(const f16x8*)(Bp + (size_t)((s * 2 + 0) * 64 + lane) * 8);
      f16x8 b1 = *(const f16x8*)(Bp + (size_t)((s * 2 + 1) * 64 + lane) * 8);
      acc0 = __builtin_amdgcn_mfma_f32_16x16x32_f16(a, b0, acc0, 0, 0, 0);
      acc1 = __builtin_amdgcn_mfma_f32_16x16x32_f16(a, b1, acc1, 0, 0, 0);
    }
    if (kc < 7) {
      int nb = (kc + 1) & 1;
#pragma unroll
      for (int g = 0; g < 4; g++) {
        f16x4 hv = {(_Float16)st[g].x, (_Float16)st[g].y, (_Float16)st[g].z,
                    (_Float16)st[g].w};
        *(f16x4*)(&As[nb][g * 16 + srow][scol]) = hv;  // write late
      }
      __syncthreads();  // single barrier per iteration
    }
  }
  int col = lane & 15;
  int rb = r0 + w * 16 + (lane >> 4) * 4;
#pragma unroll
  for (int i = 0; i < 4; i++) {
    int r = rb + i;
    if (r < N) {
      if (blockIdx.y == 0) {
        resid[(size_t)r * C_DIM + col] = acc0[i];
        if (col == 0) hl[r] = acc1[i];
      } else {
        ht_[(size_t)r * C_DIM + col] = __float2half(acc0[i]);
        if (col == 0) hr[r] = acc1[i];
      }
    }
  }
}

// ---------------------------------------------------------------------------
// K3: per-(block,bucket) histogram -> plain 2D table (NO global atomics).
// ---------------------------------------------------------------------------
__global__ __launch_bounds__(512) void hist_kernel(
    const int* __restrict__ head, unsigned* __restrict__ cnt, int E, int NB,
    int chunk) {
  __shared__ unsigned lcnt[NBMAX2];
  int tid = threadIdx.x;
  for (int b = tid; b < NB; b += 512) lcnt[b] = 0u;
  __syncthreads();
  int start = blockIdx.x * chunk;
  int end = min(E, start + chunk);
  for (int i = start + tid; i < end; i += 512)
    atomicAdd(&lcnt[((unsigned)__builtin_nontemporal_load(head + i)) >> BSHIFT],
              1u);
  __syncthreads();
  unsigned* row = cnt + (size_t)blockIdx.x * CNTW;
  for (int b = tid; b < NB; b += 512) row[b] = lcnt[b];
}

// ---------------------------------------------------------------------------
// K4a: column scan of the (block,bucket) table.
// ---------------------------------------------------------------------------
__global__ __launch_bounds__(256) void colscan_kernel(
    unsigned* __restrict__ cnt, unsigned* __restrict__ btotal, int NB) {
  int b = blockIdx.x * 256 + threadIdx.x;
  if (b >= NB) return;
  unsigned running = 0;
#pragma unroll 8
  for (int blk = 0; blk < SCB; blk++) {
    unsigned v = cnt[(size_t)blk * CNTW + b];
    cnt[(size_t)blk * CNTW + b] = running;
    running += v;
  }
  btotal[b] = running;
}

// ---------------------------------------------------------------------------
// K4b: exclusive scan of bucket totals (<=2048, one block).
// ---------------------------------------------------------------------------
__global__ __launch_bounds__(1024) void scan_kernel(
    const unsigned* __restrict__ btotal, unsigned* __restrict__ base, int NB) {
  __shared__ unsigned ps[1024];
  int t = threadIdx.x;
  unsigned a = (2 * t < NB) ? btotal[2 * t] : 0u;
  unsigned b = (2 * t + 1 < NB) ? btotal[2 * t + 1] : 0u;
  ps[t] = a + b;
  __syncthreads();
  for (int off = 1; off < 1024; off <<= 1) {
    unsigned v = (t >= off) ? ps[t - off] : 0u;
    __syncthreads();
    ps[t] += v;
    __syncthreads();
  }
  unsigned excl = ps[t] - (a + b);
  if (2 * t < NB) base[2 * t] = excl;
  if (2 * t + 1 < NB) base[2 * t + 1] = excl + a;
  if (t == 1023) base[NB] = ps[1023];
}

// ---------------------------------------------------------------------------
// K5: scatter. Full per-edge scalar chain while streaming; 8-byte record
// {local|tail, ex}.
// ---------------------------------------------------------------------------
__global__ __launch_bounds__(512) void scatter_kernel(
    const int* __restrict__ head, const int* __restrict__ tail,
    const int* __restrict__ ty, const float* __restrict__ h_l,
    const float* __restrict__ h_r, const float* __restrict__ he_tab,
    const unsigned* __restrict__ cnt, const unsigned* __restrict__ bbase,
    unsigned* __restrict__ rec, int E, int NB, int chunk, int NET) {
  __shared__ unsigned lbase[NBMAX2];
  __shared__ unsigned lcnt[NBMAX2];
  __shared__ float he_s[32];
  int tid = threadIdx.x;
  if (tid < NET) he_s[tid] = he_tab[tid];
  const unsigned* row = cnt + (size_t)blockIdx.x * CNTW;
  for (int b = tid; b < NB; b += 512) {
    lbase[b] = bbase[b] + row[b];
    lcnt[b] = 0u;
  }
  __syncthreads();
  int start = blockIdx.x * chunk;
  int end = min(E, start + chunk);
  for (int i = start + tid; i < end; i += 512) {
    unsigned h = (unsigned)__builtin_nontemporal_load(head + i);
    int tl = __builtin_nontemporal_load(tail + i);
    int t = __builtin_nontemporal_load(ty + i);
    float lg = h_l[h] + h_r[tl] + he_s[t];
    lg = lg > 0.f ? lg : 0.2f * lg;
    float ex = __expf(lg);
    unsigned b = h >> BSHIFT;
    unsigned off = atomicAdd(&lcnt[b], 1u);
    u32x2* dst = (u32x2*)(rec + 2 * (size_t)(lbase[b] + off));
    u32x2 rv;
    rv.x = ((h & 63u) << 17) | (unsigned)tl;
    rv.y = __float_as_uint(ex);
    *dst = rv;
  }
}

// ---------------------------------------------------------------------------
// K6: ZERO float atomics. LDS counting sort by local id, then 4-lane-per-node
// register segmented reduction (+2x shfl_xor), fused finalize. Overflow
// fallback for buckets > CAP (never taken here).
// ---------------------------------------------------------------------------
__global__ __launch_bounds__(256) void agg_kernel(
    const unsigned* __restrict__ rec, const unsigned* __restrict__ base,
    const __half* __restrict__ ht, const float* __restrict__ resid,
    const float* __restrict__ resb, float* __restrict__ out, int N) {
  __shared__ __align__(16) unsigned srec[CAP * 2];
  __shared__ unsigned scnt[NPB];
  __shared__ unsigned soff[NPB + 1];
  __shared__ unsigned scur[NPB];
  __shared__ float accf[NPB * 18];
  int tid = threadIdx.x;
  int b = blockIdx.x;
  int s = (int)base[b];
  int e = (int)base[b + 1];
  int cnt_all = e - s;
  int m = min(cnt_all, CAP);
  if (tid < NPB) scnt[tid] = 0u;
  for (int i = tid; i < NPB * 18; i += 256) accf[i] = 0.f;
  __syncthreads();
  for (int i = tid; i < m; i += 256)
    atomicAdd(&scnt[rec[2 * (size_t)(s + i)] >> 17], 1u);
  __syncthreads();
  if (tid < NPB) {
    unsigned v = scnt[tid];
    unsigned orig = v;
    for (int off = 1; off < NPB; off <<= 1) {
      unsigned u = __shfl_up(v, off, 64);
      if (tid >= off) v += u;
    }
    soff[tid + 1] = v;
    scur[tid] = v - orig;
    if (tid == 0) soff[0] = 0u;
  }
  __syncthreads();
  for (int i = tid; i < m; i += 256) {
    u32x2 r = *(const u32x2*)(rec + 2 * (size_t)(s + i));
    unsigned pos = atomicAdd(&scur[r.x >> 17], 1u);
    *(u32x2*)(srec + 2 * pos) = r;
  }
  for (int i = CAP + tid; i < cnt_all; i += 256) {
    u32x2 r = *(const u32x2*)(rec + 2 * (size_t)(s + i));
    int local = (int)(r.x >> 17);
    int tl = (int)(r.x & 0x1FFFFu);
    float ex = __uint_as_float(r.y);
    const uint4* hp = (const uint4*)(ht + (size_t)tl * C_DIM);
    uint4 A = hp[0], B = hp[1];
    float* a = accf + local * 18;
    U2H cv;
    float2 f;
    unsigned wv[8] = {A.x, A.y, A.z, A.w, B.x, B.y, B.z, B.w};
#pragma unroll
    for (int q = 0; q < 8; q++) {
      cv.u = wv[q];
      f = __half22float2(cv.h);
      atomicAdd(a + 2 * q, ex * f.x);
      atomicAdd(a + 2 * q + 1, ex * f.y);
    }
    atomicAdd(a + 16, ex);
  }
  __syncthreads();
  int w = tid >> 6;
  int lane = tid & 63;
  int node_l = w * 16 + (lane >> 2);
  int p = lane & 3;
  float a[CP];
#pragma unroll
  for (int k = 0; k < CP; k++) a[k] = 0.f;
  int st = (int)soff[node_l];
  int en = (int)soff[node_l + 1];
  for (int i = st + p; i < en; i += 4) {
    u32x2 r = *(const u32x2*)(srec + 2 * (size_t)i);
    int tl = (int)(r.x & 0x1FFFFu);
    float ex = __uint_as_float(r.y);
    const uint4* hp = (const uint4*)(ht + (size_t)tl * C_DIM);
    uint4 A = hp[0], B = hp[1];
    U2H cv;
    float2 f;
    unsigned wd[8] = {A.x, A.y, A.z, A.w, B.x, B.y, B.z, B.w};
#pragma unroll
    for (int q = 0; q < 8; q++) {
      cv.u = wd[q];
      f = __half22float2(cv.h);
      a[2 * q] += ex * f.x;
      a[2 * q + 1] += ex * f.y;
    }
    a[16] += ex;
  }
#pragma unroll
  for (int k = 0; k < CP; k++) {
    a[k] += __shfl_xor(a[k], 1, 64);
    a[k] += __shfl_xor(a[k], 2, 64);
  }
  if (p != 0) return;
  int node = (b << BSHIFT) + node_l;
  if (node >= N) return;
  float d = a[16] + accf[node_l * 18 + 16];
  float inv = d > 0.f ? 1.f / d : 0.f;
  const f32x4* r4 = (const f32x4*)(resid + (size_t)node * C_DIM);
  float o[C_DIM];
  float ss = 0.f;
#pragma unroll
  for (int q = 0; q < 4; q++) {
    f32x4 rr = __builtin_nontemporal_load(r4 + q);
    o[4 * q + 0] =
        (a[4 * q + 0] + accf[node_l * 18 + 4 * q + 0]) * inv + rr.x + resb[4 * q + 0];
    o[4 * q + 1] =
        (a[4 * q + 1] + accf[node_l * 18 + 4 * q + 1]) * inv + rr.y + resb[4 * q + 1];
    o[4 * q + 2] =
        (a[4 * q + 2] + accf[node_l * 18 + 4 * q + 2]) * inv + rr.z + resb[4 * q + 2];
    o[4 * q + 3] =
        (a[4 * q + 3] + accf[node_l * 18 + 4 * q + 3]) * inv + rr.w + resb[4 * q + 3];
  }
#pragma unroll
  for (int cc = 0; cc < C_DIM; cc++) ss += o[cc] * o[cc];
  float sc = 1.f / fmaxf(sqrtf(ss), 1e-12f);
  float mx = -1e30f;
#pragma unroll
  for (int cc = 0; cc < C_DIM; cc++) {
    o[cc] *= sc;
    mx = fmaxf(mx, o[cc]);
  }
  float sum = 0.f;
#pragma unroll
  for (int cc = 0; cc < C_DIM; cc++) {
    o[cc] = __expf(o[cc] - mx);
    sum += o[cc];
  }
  float isum = 1.f / sum;
  f32x4* o4 = (f32x4*)(out + (size_t)node * C_DIM);
#pragma unroll
  for (int q = 0; q < 4; q++) {
    f32x4 ov;
    ov.x = o[4 * q] * isum;
    ov.y = o[4 * q + 1] * isum;
    ov.z = o[4 * q + 2] * isum;
    ov.w = o[4 * q + 3] * isum;
    __builtin_nontemporal_store(ov, o4 + q);
  }
}

// ---------------------------------------------------------------------------
extern "C" void kernel_launch(void* const* d_in, const int* in_sizes, int n_in,
                              void* d_out, int out_size, void* d_ws,
                              size_t ws_size, hipStream_t stream) {
  const float* head_feature = (const float*)d_in[0];
  const float* tail_feature = (const float*)d_in[1];
  const int* edge_index = (const int*)d_in[2];
  const int* tmp_edge = (const int*)d_in[3];
  const float* W = (const float*)d_in[4];
  const float* We = (const float*)d_in[5];
  const float* al = (const float*)d_in[6];
  const float* ar = (const float*)d_in[7];
  const float* ae = (const float*)d_in[8];
  const float* emb = (const float*)d_in[9];
  const float* resW = (const float*)d_in[10];
  const float* resb = (const float*)d_in[11];

  const int C = in_sizes[6];           // 16
  const int IN = in_sizes[4] / C;      // 512
  const int N = in_sizes[0] / IN;      // 100000
  const int E = in_sizes[3];           // 3200000
  const int EF = in_sizes[8];          // 64
  const int NET = in_sizes[9] / EF;    // 8
  const int NB = (N + NPB - 1) / NPB;  // 1563
  (void)C; (void)IN; (void)EF; (void)ws_size; (void)out_size; (void)n_in;

  const int* head = edge_index;
  const int* tail = edge_index + E;

  float* ws = (float*)d_ws;
  float* Wh = ws;                            // 10240 f
  float* Wt = Wh + IN_F * MPAD;              // 10240 f
  float* he = Wt + IN_F * MPAD;              // 32 f
  _Float16* Bph = (_Float16*)(he + 32);      // 16384 f16 (16B-aligned)
  _Float16* Bpt = Bph + 16384;               // 16384 f16
  float* h_l = (float*)(Bpt + 16384);        // N
  float* h_r = h_l + N;                      // N
  __half* ht = (__half*)(h_r + N);           // 16N halves (32B rows, 3.2MB)
  float* resid = (float*)(ht + (size_t)C_DIM * N);  // 16N f32
  unsigned* rec = (unsigned*)(resid + (size_t)C_DIM * N);  // 2E u32
  unsigned* cnt = rec + 2 * (size_t)E;       // SCB*CNTW
  unsigned* btotal = cnt + (size_t)SCB * CNTW;  // NBMAX2
  unsigned* bbase = btotal + NBMAX2;         // NBMAX2+1

  prep_kernel<<<1, 512, 0, stream>>>(W, We, al, ar, ae, emb, resW, Wh, Wt, he,
                                     Bph, Bpt, NET);
  dim3 pg((N + 63) / 64, 2);
  proj5_kernel<<<pg, 256, 0, stream>>>(head_feature, tail_feature, Bph, Bpt,
                                       resid, h_l, ht, h_r, N);

  int chunk = (E + SCB - 1) / SCB;
  hist_kernel<<<SCB, 512, 0, stream>>>(head, cnt, E, NB, chunk);
  colscan_kernel<<<(NB + 255) / 256, 256, 0, stream>>>(cnt, btotal, NB);
  scan_kernel<<<1, 1024, 0, stream>>>(btotal, bbase, NB);
  scatter_kernel<<<SCB, 512, 0, stream>>>(head, tail, tmp_edge, h_l, h_r, he,
                                          cnt, bbase, rec, E, NB, chunk, NET);
  agg_kernel<<<NB, 256, 0, stream>>>(rec, bbase, ht, resid, resb,
                                     (float*)d_out, N);
}

// Round 14
// 278.327 us; speedup vs baseline: 1.0063x; 1.0063x over previous
//
#include <hip/hip_runtime.h>
#include <hip/hip_fp16.h>
#include <math.h>

#define IN_F 512
#define C_DIM 16
#define CP 17        // C + 1 (extra attention column)
#define MPAD 20      // padded row stride for combined matrices (16B-aligned)
#define EF_DIM 64
#define BSHIFT 6     // nodes-per-bucket shift
#define NPB 64       // nodes per bucket; local id fits in 6 bits
#define NBMAX2 2048  // max buckets (N <= 131072: tail fits 17 bits)
#define CNTW 2048    // cnt table row width
#define SCB 512      // scatter/hist partition blocks
#define CAP 2560     // per-bucket sorted-record capacity
// record: { local(6)[17:22] | tail(17)[0:16] , float ex }

typedef float f32x4 __attribute__((ext_vector_type(4)));
typedef unsigned u32x2 __attribute__((ext_vector_type(2)));
typedef unsigned u32x4 __attribute__((ext_vector_type(4)));
typedef _Float16 f16x4 __attribute__((ext_vector_type(4)));
typedef _Float16 f16x8 __attribute__((ext_vector_type(8)));

union U2H { unsigned u; __half2 h; };

typedef const unsigned __attribute__((address_space(1)))* gas_u32;
typedef unsigned __attribute__((address_space(3)))* las_u32;

// direct global->LDS 16B async copy; LDS dest = uniform base + lane*16
__device__ __forceinline__ void gld16(const float* g, float* l) {
  __builtin_amdgcn_global_load_lds((gas_u32)g, (las_u32)l, 16, 0, 0);
}

// ---------------------------------------------------------------------------
// K0: prep. Combined f32 matrices, 8-entry edge-type table, and
// fragment-packed f16 B matrices for the MFMA proj (layout per R12).
// ---------------------------------------------------------------------------
__global__ __launch_bounds__(512) void prep_kernel(
    const float* __restrict__ W, const float* __restrict__ We,
    const float* __restrict__ al, const float* __restrict__ ar,
    const float* __restrict__ ae, const float* __restrict__ emb,
    const float* __restrict__ resW,
    float* __restrict__ Wh, float* __restrict__ Wt, float* __restrict__ he,
    _Float16* __restrict__ Bph, _Float16* __restrict__ Bpt, int NET) {
  __shared__ float v[EF_DIM];
  int t = threadIdx.x;  // 0..511 == k index for phase 1
  float wl = 0.f, wr = 0.f;
#pragma unroll
  for (int c = 0; c < C_DIM; c++) {
    float wv = W[t * C_DIM + c];
    wl += wv * al[c];
    wr += wv * ar[c];
    Wt[t * MPAD + c] = wv;
    Wh[t * MPAD + c] = resW[t * C_DIM + c];
  }
  Wh[t * MPAD + C_DIM] = wl;
  Wt[t * MPAD + C_DIM] = wr;
  if (t < EF_DIM) {
    float s = 0.f;
    for (int f = 0; f < EF_DIM; f++) s += We[t * EF_DIM + f] * ae[f];
    v[t] = s;
  }
  __syncthreads();
  if (t < NET) {
    float s = 0.f;
    for (int k = 0; k < EF_DIM; k++) s += emb[t * EF_DIM + k] * v[k];
    he[t] = s;
  }
  // phase 2: MFMA B fragments (16384 f16 per matrix)
  for (int i = 0; i < 32; i++) {
    int flat = t + 512 * i;
    int j = flat & 7;
    int l = (flat >> 3) & 63;
    int n = (flat >> 9) & 1;
    int s = flat >> 10;  // 0..15
    int k = 32 * s + ((l >> 4) << 3) + j;
    int c = (l & 15) + 16 * n;
    float bh = 0.f, bt = 0.f;
    if (c < C_DIM) {
      bh = resW[k * C_DIM + c];
      bt = W[k * C_DIM + c];
    } else if (c == C_DIM) {
      for (int cc = 0; cc < C_DIM; cc++) {
        float wv = W[k * C_DIM + cc];
        bh += wv * al[cc];
        bt += wv * ar[cc];
      }
    }
    Bph[flat] = (_Float16)bh;
    Bpt[flat] = (_Float16)bt;
  }
}

// ---------------------------------------------------------------------------
// K1: proj6 -- MFMA GEMM staged via global_load_lds (direct L2->LDS, no
// VGPR/L1 return path). Six reg-staged structures all converged at
// ~3.1TB/s demand reads (= m13 copy read rate, ~5B/cy/CU) -- suspected
// L1 outstanding-miss cap. gload_lds writes LINEAR LDS (uniform base +
// lane*16), so conflict-free A-reads use a BOTH-SIDES swizzle (rule #21):
// logical (row r, 16B-unit c) stored at unit s = r*16 + (c ^ (r&7));
// staging pre-swizzles the per-lane GLOBAL source; ds_read_b128 applies
// the same XOR. f32 in LDS; cvt to f16 in regs before MFMA (VALU idle).
// Double-buffered (2x16KB), one barrier/chunk (syncthreads drains vmcnt).
// ---------------------------------------------------------------------------
__global__ __launch_bounds__(256) void proj6_kernel(
    const float* __restrict__ hf, const float* __restrict__ tf,
    const _Float16* __restrict__ Bph, const _Float16* __restrict__ Bpt,
    float* __restrict__ resid, float* __restrict__ hl,
    __half* __restrict__ ht_, float* __restrict__ hr, int N) {
  __shared__ float As[2][4096];  // 2 x 16KB, linear (gload_lds requirement)
  int t = threadIdx.x;
  int w = __builtin_amdgcn_readfirstlane(t >> 6);
  int lane = t & 63;
  int r0 = blockIdx.x * 64;
  const float* feat = blockIdx.y ? tf : hf;     // blockIdx-uniform (R11)
  const _Float16* Bp = blockIdx.y ? Bpt : Bph;
  f32x4 acc0 = {0.f, 0.f, 0.f, 0.f};
  f32x4 acc1 = {0.f, 0.f, 0.f, 0.f};
  // staging: instr (w,g) fills units [(w*4+g)*64, +64); lane l -> unit base+l
  const float* sg_src[4];
#pragma unroll
  for (int g = 0; g < 4; g++) {
    int u = (w * 4 + g) * 64 + lane;
    int r = u >> 4;
    int c = (u & 15) ^ (r & 7);  // inverse swizzle on the global source
    int gr = min(r0 + r, N - 1);
    sg_src[g] = feat + (size_t)gr * IN_F + c * 4;
  }
  // A-fragment swizzled unit indices: s2 k-half, h 16B-unit within 32B
  int row = w * 16 + (lane & 15);
  int sA[2][2];
#pragma unroll
  for (int s2 = 0; s2 < 2; s2++)
#pragma unroll
    for (int h = 0; h < 2; h++)
      sA[s2][h] = row * 16 + ((s2 * 8 + (lane >> 4) * 2 + h) ^ (row & 7));
  // prologue: stage chunk 0
#pragma unroll
  for (int g = 0; g < 4; g++)
    gld16(sg_src[g], &As[0][(w * 4 + g) * 256]);
  __syncthreads();
#pragma unroll
  for (int kc = 0; kc < 8; kc++) {
    if (kc < 7) {
      int nb = (kc + 1) & 1;
#pragma unroll
      for (int g = 0; g < 4; g++)
        gld16(sg_src[g] + (kc + 1) * 64, &As[nb][(w * 4 + g) * 256]);
    }
    const float* ab = As[kc & 1];
#pragma unroll
    for (int s2 = 0; s2 < 2; s2++) {
      f32x4 lo = *(const f32x4*)(ab + sA[s2][0] * 4);
      f32x4 hi = *(const f32x4*)(ab + sA[s2][1] * 4);
      f16x8 a = {(_Float16)lo.x, (_Float16)lo.y, (_Float16)lo.z,
                 (_Float16)lo.w, (_Float16)hi.x, (_Float16)hi.y,
                 (_Float16)hi.z, (_Float16)hi.w};
      int s = kc * 2 + s2;
      f16x8 b0 = *(const f16x8*)(Bp + (size_t)((s * 2 + 0) * 64 + lane) * 8);
      f16x8 b1 = *(const f16x8*)(Bp + (size_t)((s * 2 + 1) * 64 + lane) * 8);
      acc0 = __builtin_amdgcn_mfma_f32_16x16x32_f16(a, b0, acc0, 0, 0, 0);
      acc1 = __builtin_amdgcn_mfma_f32_16x16x32_f16(a, b1, acc1, 0, 0, 0);
    }
    __syncthreads();  // drains vmcnt -> next chunk resident; LDS reuse safe
  }
  int col = lane & 15;
  int rb = r0 + w * 16 + (lane >> 4) * 4;
#pragma unroll
  for (int i = 0; i < 4; i++) {
    int r = rb + i;
    if (r < N) {
      if (blockIdx.y == 0) {
        resid[(size_t)r * C_DIM + col] = acc0[i];
        if (col == 0) hl[r] = acc1[i];
      } else {
        ht_[(size_t)r * C_DIM + col] = __float2half(acc0[i]);
        if (col == 0) hr[r] = acc1[i];
      }
    }
  }
}

// ---------------------------------------------------------------------------
// K3: per-(block,bucket) histogram -> plain 2D table (NO global atomics).
// ---------------------------------------------------------------------------
__global__ __launch_bounds__(512) void hist_kernel(
    const int* __restrict__ head, unsigned* __restrict__ cnt, int E, int NB,
    int chunk) {
  __shared__ unsigned lcnt[NBMAX2];
  int tid = threadIdx.x;
  for (int b = tid; b < NB; b += 512) lcnt[b] = 0u;
  __syncthreads();
  int start = blockIdx.x * chunk;
  int end = min(E, start + chunk);
  for (int i = start + tid; i < end; i += 512)
    atomicAdd(&lcnt[((unsigned)__builtin_nontemporal_load(head + i)) >> BSHIFT],
              1u);
  __syncthreads();
  unsigned* row = cnt + (size_t)blockIdx.x * CNTW;
  for (int b = tid; b < NB; b += 512) row[b] = lcnt[b];
}

// ---------------------------------------------------------------------------
// K4a: column scan of the (block,bucket) table.
// ---------------------------------------------------------------------------
__global__ __launch_bounds__(256) void colscan_kernel(
    unsigned* __restrict__ cnt, unsigned* __restrict__ btotal, int NB) {
  int b = blockIdx.x * 256 + threadIdx.x;
  if (b >= NB) return;
  unsigned running = 0;
#pragma unroll 8
  for (int blk = 0; blk < SCB; blk++) {
    unsigned v = cnt[(size_t)blk * CNTW + b];
    cnt[(size_t)blk * CNTW + b] = running;
    running += v;
  }
  btotal[b] = running;
}

// ---------------------------------------------------------------------------
// K4b: exclusive scan of bucket totals (<=2048, one block).
// ---------------------------------------------------------------------------
__global__ __launch_bounds__(1024) void scan_kernel(
    const unsigned* __restrict__ btotal, unsigned* __restrict__ base, int NB) {
  __shared__ unsigned ps[1024];
  int t = threadIdx.x;
  unsigned a = (2 * t < NB) ? btotal[2 * t] : 0u;
  unsigned b = (2 * t + 1 < NB) ? btotal[2 * t + 1] : 0u;
  ps[t] = a + b;
  __syncthreads();
  for (int off = 1; off < 1024; off <<= 1) {
    unsigned v = (t >= off) ? ps[t - off] : 0u;
    __syncthreads();
    ps[t] += v;
    __syncthreads();
  }
  unsigned excl = ps[t] - (a + b);
  if (2 * t < NB) base[2 * t] = excl;
  if (2 * t + 1 < NB) base[2 * t + 1] = excl + a;
  if (t == 1023) base[NB] = ps[1023];
}

// ---------------------------------------------------------------------------
// K5: scatter. Full per-edge scalar chain while streaming; 8-byte record
// {local|tail, ex}.
// ---------------------------------------------------------------------------
__global__ __launch_bounds__(512) void scatter_kernel(
    const int* __restrict__ head, const int* __restrict__ tail,
    const int* __restrict__ ty, const float* __restrict__ h_l,
    const float* __restrict__ h_r, const float* __restrict__ he_tab,
    const unsigned* __restrict__ cnt, const unsigned* __restrict__ bbase,
    unsigned* __restrict__ rec, int E, int NB, int chunk, int NET) {
  __shared__ unsigned lbase[NBMAX2];
  __shared__ unsigned lcnt[NBMAX2];
  __shared__ float he_s[32];
  int tid = threadIdx.x;
  if (tid < NET) he_s[tid] = he_tab[tid];
  const unsigned* row = cnt + (size_t)blockIdx.x * CNTW;
  for (int b = tid; b < NB; b += 512) {
    lbase[b] = bbase[b] + row[b];
    lcnt[b] = 0u;
  }
  __syncthreads();
  int start = blockIdx.x * chunk;
  int end = min(E, start + chunk);
  for (int i = start + tid; i < end; i += 512) {
    unsigned h = (unsigned)__builtin_nontemporal_load(head + i);
    int tl = __builtin_nontemporal_load(tail + i);
    int t = __builtin_nontemporal_load(ty + i);
    float lg = h_l[h] + h_r[tl] + he_s[t];
    lg = lg > 0.f ? lg : 0.2f * lg;
    float ex = __expf(lg);
    unsigned b = h >> BSHIFT;
    unsigned off = atomicAdd(&lcnt[b], 1u);
    u32x2* dst = (u32x2*)(rec + 2 * (size_t)(lbase[b] + off));
    u32x2 rv;
    rv.x = ((h & 63u) << 17) | (unsigned)tl;
    rv.y = __float_as_uint(ex);
    *dst = rv;
  }
}

// ---------------------------------------------------------------------------
// K6: ZERO float atomics. LDS counting sort by local id, then 4-lane-per-node
// register segmented reduction (+2x shfl_xor), fused finalize. Overflow
// fallback for buckets > CAP (never taken here).
// ---------------------------------------------------------------------------
__global__ __launch_bounds__(256) void agg_kernel(
    const unsigned* __restrict__ rec, const unsigned* __restrict__ base,
    const __half* __restrict__ ht, const float* __restrict__ resid,
    const float* __restrict__ resb, float* __restrict__ out, int N) {
  __shared__ __align__(16) unsigned srec[CAP * 2];
  __shared__ unsigned scnt[NPB];
  __shared__ unsigned soff[NPB + 1];
  __shared__ unsigned scur[NPB];
  __shared__ float accf[NPB * 18];
  int tid = threadIdx.x;
  int b = blockIdx.x;
  int s = (int)base[b];
  int e = (int)base[b + 1];
  int cnt_all = e - s;
  int m = min(cnt_all, CAP);
  if (tid < NPB) scnt[tid] = 0u;
  for (int i = tid; i < NPB * 18; i += 256) accf[i] = 0.f;
  __syncthreads();
  for (int i = tid; i < m; i += 256)
    atomicAdd(&scnt[rec[2 * (size_t)(s + i)] >> 17], 1u);
  __syncthreads();
  if (tid < NPB) {
    unsigned v = scnt[tid];
    unsigned orig = v;
    for (int off = 1; off < NPB; off <<= 1) {
      unsigned u = __shfl_up(v, off, 64);
      if (tid >= off) v += u;
    }
    soff[tid + 1] = v;
    scur[tid] = v - orig;
    if (tid == 0) soff[0] = 0u;
  }
  __syncthreads();
  for (int i = tid; i < m; i += 256) {
    u32x2 r = *(const u32x2*)(rec + 2 * (size_t)(s + i));
    unsigned pos = atomicAdd(&scur[r.x >> 17], 1u);
    *(u32x2*)(srec + 2 * pos) = r;
  }
  for (int i = CAP + tid; i < cnt_all; i += 256) {
    u32x2 r = *(const u32x2*)(rec + 2 * (size_t)(s + i));
    int local = (int)(r.x >> 17);
    int tl = (int)(r.x & 0x1FFFFu);
    float ex = __uint_as_float(r.y);
    const uint4* hp = (const uint4*)(ht + (size_t)tl * C_DIM);
    uint4 A = hp[0], B = hp[1];
    float* a = accf + local * 18;
    U2H cv;
    float2 f;
    unsigned wv[8] = {A.x, A.y, A.z, A.w, B.x, B.y, B.z, B.w};
#pragma unroll
    for (int q = 0; q < 8; q++) {
      cv.u = wv[q];
      f = __half22float2(cv.h);
      atomicAdd(a + 2 * q, ex * f.x);
      atomicAdd(a + 2 * q + 1, ex * f.y);
    }
    atomicAdd(a + 16, ex);
  }
  __syncthreads();
  int w = tid >> 6;
  int lane = tid & 63;
  int node_l = w * 16 + (lane >> 2);
  int p = lane & 3;
  float a[CP];
#pragma unroll
  for (int k = 0; k < CP; k++) a[k] = 0.f;
  int st = (int)soff[node_l];
  int en = (int)soff[node_l + 1];
  for (int i = st + p; i < en; i += 4) {
    u32x2 r = *(const u32x2*)(srec + 2 * (size_t)i);
    int tl = (int)(r.x & 0x1FFFFu);
    float ex = __uint_as_float(r.y);
    const uint4* hp = (const uint4*)(ht + (size_t)tl * C_DIM);
    uint4 A = hp[0], B = hp[1];
    U2H cv;
    float2 f;
    unsigned wd[8] = {A.x, A.y, A.z, A.w, B.x, B.y, B.z, B.w};
#pragma unroll
    for (int q = 0; q < 8; q++) {
      cv.u = wd[q];
      f = __half22float2(cv.h);
      a[2 * q] += ex * f.x;
      a[2 * q + 1] += ex * f.y;
    }
    a[16] += ex;
  }
#pragma unroll
  for (int k = 0; k < CP; k++) {
    a[k] += __shfl_xor(a[k], 1, 64);
    a[k] += __shfl_xor(a[k], 2, 64);
  }
  if (p != 0) return;
  int node = (b << BSHIFT) + node_l;
  if (node >= N) return;
  float d = a[16] + accf[node_l * 18 + 16];
  float inv = d > 0.f ? 1.f / d : 0.f;
  const f32x4* r4 = (const f32x4*)(resid + (size_t)node * C_DIM);
  float o[C_DIM];
  float ss = 0.f;
#pragma unroll
  for (int q = 0; q < 4; q++) {
    f32x4 rr = __builtin_nontemporal_load(r4 + q);
    o[4 * q + 0] =
        (a[4 * q + 0] + accf[node_l * 18 + 4 * q + 0]) * inv + rr.x + resb[4 * q + 0];
    o[4 * q + 1] =
        (a[4 * q + 1] + accf[node_l * 18 + 4 * q + 1]) * inv + rr.y + resb[4 * q + 1];
    o[4 * q + 2] =
        (a[4 * q + 2] + accf[node_l * 18 + 4 * q + 2]) * inv + rr.z + resb[4 * q + 2];
    o[4 * q + 3] =
        (a[4 * q + 3] + accf[node_l * 18 + 4 * q + 3]) * inv + rr.w + resb[4 * q + 3];
  }
#pragma unroll
  for (int cc = 0; cc < C_DIM; cc++) ss += o[cc] * o[cc];
  float sc = 1.f / fmaxf(sqrtf(ss), 1e-12f);
  float mx = -1e30f;
#pragma unroll
  for (int cc = 0; cc < C_DIM; cc++) {
    o[cc] *= sc;
    mx = fmaxf(mx, o[cc]);
  }
  float sum = 0.f;
#pragma unroll
  for (int cc = 0; cc < C_DIM; cc++) {
    o[cc] = __expf(o[cc] - mx);
    sum += o[cc];
  }
  float isum = 1.f / sum;
  f32x4* o4 = (f32x4*)(out + (size_t)node * C_DIM);
#pragma unroll
  for (int q = 0; q < 4; q++) {
    f32x4 ov;
    ov.x = o[4 * q] * isum;
    ov.y = o[4 * q + 1] * isum;
    ov.z = o[4 * q + 2] * isum;
    ov.w = o[4 * q + 3] * isum;
    __builtin_nontemporal_store(ov, o4 + q);
  }
}

// ---------------------------------------------------------------------------
extern "C" void kernel_launch(void* const* d_in, const int* in_sizes, int n_in,
                              void* d_out, int out_size, void* d_ws,
                              size_t ws_size, hipStream_t stream) {
  const float* head_feature = (const float*)d_in[0];
  const float* tail_feature = (const float*)d_in[1];
  const int* edge_index = (const int*)d_in[2];
  const int* tmp_edge = (const int*)d_in[3];
  const float* W = (const float*)d_in[4];
  const float* We = (const float*)d_in[5];
  const float* al = (const float*)d_in[6];
  const float* ar = (const float*)d_in[7];
  const float* ae = (const float*)d_in[8];
  const float* emb = (const float*)d_in[9];
  const float* resW = (const float*)d_in[10];
  const float* resb = (const float*)d_in[11];

  const int C = in_sizes[6];           // 16
  const int IN = in_sizes[4] / C;      // 512
  const int N = in_sizes[0] / IN;      // 100000
  const int E = in_sizes[3];           // 3200000
  const int EF = in_sizes[8];          // 64
  const int NET = in_sizes[9] / EF;    // 8
  const int NB = (N + NPB - 1) / NPB;  // 1563
  (void)C; (void)IN; (void)EF; (void)ws_size; (void)out_size; (void)n_in;

  const int* head = edge_index;
  const int* tail = edge_index + E;

  float* ws = (float*)d_ws;
  float* Wh = ws;                            // 10240 f
  float* Wt = Wh + IN_F * MPAD;              // 10240 f
  float* he = Wt + IN_F * MPAD;              // 32 f
  _Float16* Bph = (_Float16*)(he + 32);      // 16384 f16 (16B-aligned)
  _Float16* Bpt = Bph + 16384;               // 16384 f16
  float* h_l = (float*)(Bpt + 16384);        // N
  float* h_r = h_l + N;                      // N
  __half* ht = (__half*)(h_r + N);           // 16N halves (32B rows, 3.2MB)
  float* resid = (float*)(ht + (size_t)C_DIM * N);  // 16N f32
  unsigned* rec = (unsigned*)(resid + (size_t)C_DIM * N);  // 2E u32
  unsigned* cnt = rec + 2 * (size_t)E;       // SCB*CNTW
  unsigned* btotal = cnt + (size_t)SCB * CNTW;  // NBMAX2
  unsigned* bbase = btotal + NBMAX2;         // NBMAX2+1

  prep_kernel<<<1, 512, 0, stream>>>(W, We, al, ar, ae, emb, resW, Wh, Wt, he,
                                     Bph, Bpt, NET);
  dim3 pg((N + 63) / 64, 2);
  proj6_kernel<<<pg, 256, 0, stream>>>(head_feature, tail_feature, Bph, Bpt,
                                       resid, h_l, ht, h_r, N);

  int chunk = (E + SCB - 1) / SCB;
  hist_kernel<<<SCB, 512, 0, stream>>>(head, cnt, E, NB, chunk);
  colscan_kernel<<<(NB + 255) / 256, 256, 0, stream>>>(cnt, btotal, NB);
  scan_kernel<<<1, 1024, 0, stream>>>(btotal, bbase, NB);
  scatter_kernel<<<SCB, 512, 0, stream>>>(head, tail, tmp_edge, h_l, h_r, he,
                                          cnt, bbase, rec, E, NB, chunk, NET);
  agg_kernel<<<NB, 256, 0, stream>>>(rec, bbase, ht, resid, resb,
                                     (float*)d_out, N);
}

// Round 15
// 243.960 us; speedup vs baseline: 1.1480x; 1.1409x over previous
//
#include <hip/hip_runtime.h>
#include <hip/hip_fp16.h>
#include <math.h>

#define IN_F 512
#define C_DIM 16
#define EF_DIM 64
#define BSHIFT 6     // nodes-per-bucket shift
#define NPB 64       // nodes per bucket; local id fits in 6 bits
#define NBMAX2 2048  // max buckets (N <= 131072: tail fits 17 bits)
#define CNTW 2048    // cnt table row width
#define SCB 512      // scatter/hist partition blocks
#define CAP 2560     // per-bucket sorted-record capacity
// record (4B): local(6)[25:20] | type(3)[19:17] | tail(17)[16:0]

typedef float f32x4 __attribute__((ext_vector_type(4)));
typedef unsigned u32x2 __attribute__((ext_vector_type(2)));
typedef _Float16 f16x8 __attribute__((ext_vector_type(8)));

union U2H { unsigned u; __half2 h; };

typedef const unsigned __attribute__((address_space(1)))* gas_u32;
typedef unsigned __attribute__((address_space(3)))* las_u32;

__device__ __forceinline__ void gld16(const float* g, float* l) {
  __builtin_amdgcn_global_load_lds((gas_u32)g, (las_u32)l, 16, 0, 0);
}

// ---------------------------------------------------------------------------
// K0: prep. Edge-type logit table he[8]; attention-column weight vectors
// wlt/wrt[512] (f32); and 16KB fragment-packed f16 B tables (cols 0-15
// ONLY -- R14's 32KB table was the size of L1 and thrashed; the attention
// column moved to the VALU in proj7).
// Bp[(s*64+l)*8+j] = B[32s+(l>>4)*8+j][l&15], B = resW (head) / W (tail).
// ---------------------------------------------------------------------------
__global__ __launch_bounds__(512) void prep_kernel(
    const float* __restrict__ W, const float* __restrict__ We,
    const float* __restrict__ al, const float* __restrict__ ar,
    const float* __restrict__ ae, const float* __restrict__ emb,
    const float* __restrict__ resW, float* __restrict__ he,
    _Float16* __restrict__ Bph, _Float16* __restrict__ Bpt,
    float* __restrict__ wlt, float* __restrict__ wrt, int NET) {
  __shared__ float v[EF_DIM];
  int t = threadIdx.x;  // 0..511 == k index
  float wl = 0.f, wr = 0.f;
#pragma unroll
  for (int c = 0; c < C_DIM; c++) {
    float wv = W[t * C_DIM + c];
    wl += wv * al[c];
    wr += wv * ar[c];
  }
  wlt[t] = wl;
  wrt[t] = wr;
  if (t < EF_DIM) {
    float s = 0.f;
    for (int f = 0; f < EF_DIM; f++) s += We[t * EF_DIM + f] * ae[f];
    v[t] = s;
  }
  __syncthreads();
  if (t < NET) {
    float s = 0.f;
    for (int k = 0; k < EF_DIM; k++) s += emb[t * EF_DIM + k] * v[k];
    he[t] = s;
  }
  // B fragments: 8192 f16 per matrix (16KB)
  for (int i = 0; i < 16; i++) {
    int flat = t + 512 * i;
    int j = flat & 7;
    int l = (flat >> 3) & 63;
    int s = flat >> 9;  // 0..15
    int k = 32 * s + ((l >> 4) << 3) + j;
    int c = l & 15;
    Bph[flat] = (_Float16)resW[k * C_DIM + c];
    Bpt[flat] = (_Float16)W[k * C_DIM + c];
  }
}

// ---------------------------------------------------------------------------
// K1: proj7 -- MFMA GEMM, gload_lds staging (R14), 16KB L1-resident B.
// acc0 (16 channels) via mfma_f32_16x16x32_f16 with the halved B table;
// attention column via VALU: per lane, dot of its A-fragment f32 values
// (pre-cvt) with wl[k] (2KB L1 table), reduced across the 4 k-groups by
// shfl_xor(16)/shfl_xor(32); lanes 0-15 store h_l/h_r (now full f32).
// ---------------------------------------------------------------------------
__global__ __launch_bounds__(256) void proj7_kernel(
    const float* __restrict__ hf, const float* __restrict__ tf,
    const _Float16* __restrict__ Bph, const _Float16* __restrict__ Bpt,
    const float* __restrict__ wlt, const float* __restrict__ wrt,
    float* __restrict__ resid, float* __restrict__ hl,
    __half* __restrict__ ht_, float* __restrict__ hr, int N) {
  __shared__ float As[2][4096];  // 2 x 16KB, linear (gload_lds requirement)
  int t = threadIdx.x;
  int w = __builtin_amdgcn_readfirstlane(t >> 6);
  int lane = t & 63;
  int r0 = blockIdx.x * 64;
  const float* feat = blockIdx.y ? tf : hf;   // blockIdx-uniform (R11)
  const _Float16* Bp = blockIdx.y ? Bpt : Bph;
  const float* wv = blockIdx.y ? wrt : wlt;
  f32x4 acc0 = {0.f, 0.f, 0.f, 0.f};
  float acc1 = 0.f;
  // staging sources: pre-swizzled global addresses (rule #21, as R14)
  const float* sg_src[4];
#pragma unroll
  for (int g = 0; g < 4; g++) {
    int u = (w * 4 + g) * 64 + lane;
    int r = u >> 4;
    int c = (u & 15) ^ (r & 7);
    int gr = min(r0 + r, N - 1);
    sg_src[g] = feat + (size_t)gr * IN_F + c * 4;
  }
  int row = w * 16 + (lane & 15);
  int sA[2][2];
#pragma unroll
  for (int s2 = 0; s2 < 2; s2++)
#pragma unroll
    for (int h = 0; h < 2; h++)
      sA[s2][h] = row * 16 + ((s2 * 8 + (lane >> 4) * 2 + h) ^ (row & 7));
  const float* wvp = wv + (lane >> 4) * 8;  // lane's k-slice base
  // prologue: stage chunk 0
#pragma unroll
  for (int g = 0; g < 4; g++) gld16(sg_src[g], &As[0][(w * 4 + g) * 256]);
  __syncthreads();
#pragma unroll
  for (int kc = 0; kc < 8; kc++) {
    if (kc < 7) {
      int nb = (kc + 1) & 1;
#pragma unroll
      for (int g = 0; g < 4; g++)
        gld16(sg_src[g] + (kc + 1) * 64, &As[nb][(w * 4 + g) * 256]);
    }
    const float* ab = As[kc & 1];
#pragma unroll
    for (int s2 = 0; s2 < 2; s2++) {
      f32x4 lo = *(const f32x4*)(ab + sA[s2][0] * 4);
      f32x4 hi = *(const f32x4*)(ab + sA[s2][1] * 4);
      f16x8 a = {(_Float16)lo.x, (_Float16)lo.y, (_Float16)lo.z,
                 (_Float16)lo.w, (_Float16)hi.x, (_Float16)hi.y,
                 (_Float16)hi.z, (_Float16)hi.w};
      int s = kc * 2 + s2;
      f16x8 b0 = *(const f16x8*)(Bp + (size_t)(s * 64 + lane) * 8);
      acc0 = __builtin_amdgcn_mfma_f32_16x16x32_f16(a, b0, acc0, 0, 0, 0);
      // attention column on VALU (f32, exact)
      f32x4 wa = *(const f32x4*)(wvp + kc * 64 + s2 * 32);
      f32x4 wb = *(const f32x4*)(wvp + kc * 64 + s2 * 32 + 4);
      acc1 += lo.x * wa.x + lo.y * wa.y + lo.z * wa.z + lo.w * wa.w +
              hi.x * wb.x + hi.y * wb.y + hi.z * wb.z + hi.w * wb.w;
    }
    __syncthreads();
  }
  // reduce acc1 across the 4 k-groups (lanes r, r+16, r+32, r+48)
  acc1 += __shfl_xor(acc1, 16, 64);
  acc1 += __shfl_xor(acc1, 32, 64);
  int col = lane & 15;
  int rb = r0 + w * 16 + (lane >> 4) * 4;
#pragma unroll
  for (int i = 0; i < 4; i++) {
    int r = rb + i;
    if (r < N) {
      if (blockIdx.y == 0)
        resid[(size_t)r * C_DIM + col] = acc0[i];
      else
        ht_[(size_t)r * C_DIM + col] = __float2half(acc0[i]);
    }
  }
  if (lane < 16) {
    int r = r0 + w * 16 + lane;
    if (r < N) {
      if (blockIdx.y == 0)
        hl[r] = acc1;
      else
        hr[r] = acc1;
    }
  }
}

// ---------------------------------------------------------------------------
// K3: per-(block,bucket) histogram -> plain 2D table (NO global atomics).
// ---------------------------------------------------------------------------
__global__ __launch_bounds__(512) void hist_kernel(
    const int* __restrict__ head, unsigned* __restrict__ cnt, int E, int NB,
    int chunk) {
  __shared__ unsigned lcnt[NBMAX2];
  int tid = threadIdx.x;
  for (int b = tid; b < NB; b += 512) lcnt[b] = 0u;
  __syncthreads();
  int start = blockIdx.x * chunk;
  int end = min(E, start + chunk);
  for (int i = start + tid; i < end; i += 512)
    atomicAdd(&lcnt[((unsigned)__builtin_nontemporal_load(head + i)) >> BSHIFT],
              1u);
  __syncthreads();
  unsigned* row = cnt + (size_t)blockIdx.x * CNTW;
  for (int b = tid; b < NB; b += 512) row[b] = lcnt[b];
}

// ---------------------------------------------------------------------------
// K4a: column scan of the (block,bucket) table.
// ---------------------------------------------------------------------------
__global__ __launch_bounds__(256) void colscan_kernel(
    unsigned* __restrict__ cnt, unsigned* __restrict__ btotal, int NB) {
  int b = blockIdx.x * 256 + threadIdx.x;
  if (b >= NB) return;
  unsigned running = 0;
#pragma unroll 8
  for (int blk = 0; blk < SCB; blk++) {
    unsigned v = cnt[(size_t)blk * CNTW + b];
    cnt[(size_t)blk * CNTW + b] = running;
    running += v;
  }
  btotal[b] = running;
}

// ---------------------------------------------------------------------------
// K4b: exclusive scan of bucket totals (<=2048, one block).
// ---------------------------------------------------------------------------
__global__ __launch_bounds__(1024) void scan_kernel(
    const unsigned* __restrict__ btotal, unsigned* __restrict__ base, int NB) {
  __shared__ unsigned ps[1024];
  int t = threadIdx.x;
  unsigned a = (2 * t < NB) ? btotal[2 * t] : 0u;
  unsigned b = (2 * t + 1 < NB) ? btotal[2 * t + 1] : 0u;
  ps[t] = a + b;
  __syncthreads();
  for (int off = 1; off < 1024; off <<= 1) {
    unsigned v = (t >= off) ? ps[t - off] : 0u;
    __syncthreads();
    ps[t] += v;
    __syncthreads();
  }
  unsigned excl = ps[t] - (a + b);
  if (2 * t < NB) base[2 * t] = excl;
  if (2 * t + 1 < NB) base[2 * t + 1] = excl + a;
  if (t == 1023) base[NB] = ps[1023];
}

// ---------------------------------------------------------------------------
// K5: scatter v2 -- PURE PERMUTATION. No h_l/h_r gathers, no exp (moved to
// agg, where h_l is an L1-resident 256B window). 4-byte record
// local|type|tail; write traffic halved to 12.8MB.
// ---------------------------------------------------------------------------
__global__ __launch_bounds__(512) void scatter_kernel(
    const int* __restrict__ head, const int* __restrict__ tail,
    const int* __restrict__ ty, const unsigned* __restrict__ cnt,
    const unsigned* __restrict__ bbase, unsigned* __restrict__ rec, int E,
    int NB, int chunk) {
  __shared__ unsigned lbase[NBMAX2];
  __shared__ unsigned lcnt[NBMAX2];
  int tid = threadIdx.x;
  const unsigned* row = cnt + (size_t)blockIdx.x * CNTW;
  for (int b = tid; b < NB; b += 512) {
    lbase[b] = bbase[b] + row[b];
    lcnt[b] = 0u;
  }
  __syncthreads();
  int start = blockIdx.x * chunk;
  int end = min(E, start + chunk);
  for (int i = start + tid; i < end; i += 512) {
    unsigned h = (unsigned)__builtin_nontemporal_load(head + i);
    unsigned tl = (unsigned)__builtin_nontemporal_load(tail + i);
    unsigned t = (unsigned)__builtin_nontemporal_load(ty + i);
    unsigned b = h >> BSHIFT;
    unsigned off = atomicAdd(&lcnt[b], 1u);
    rec[lbase[b] + off] = ((h & 63u) << 20) | ((t & 7u) << 17) | tl;
  }
}

// ---------------------------------------------------------------------------
// K6: agg v3 -- 4B records. LDS counting sort by local id, then
// 4-lane-per-node register segmented reduction; logit recomputed here:
// h_l from an LDS-cached 64-float window, h_r random 4B L2 gather, he LDS.
// Zero float atomics. Overflow fallback for buckets > CAP (never taken).
// ---------------------------------------------------------------------------
__global__ __launch_bounds__(256) void agg_kernel(
    const unsigned* __restrict__ rec, const unsigned* __restrict__ base,
    const __half* __restrict__ ht, const float* __restrict__ h_l,
    const float* __restrict__ h_r, const float* __restrict__ he_tab,
    const float* __restrict__ resid, const float* __restrict__ resb,
    float* __restrict__ out, int N, int NET) {
  __shared__ unsigned srec[CAP];
  __shared__ unsigned scnt[NPB];
  __shared__ unsigned soff[NPB + 1];
  __shared__ unsigned scur[NPB];
  __shared__ float accf[NPB * 18];
  __shared__ float hl_s[NPB];
  __shared__ float he_s[8];
  int tid = threadIdx.x;
  int b = blockIdx.x;
  int nodebase = b << BSHIFT;
  int s = (int)base[b];
  int e = (int)base[b + 1];
  int cnt_all = e - s;
  int m = min(cnt_all, CAP);
  if (tid < NPB) {
    scnt[tid] = 0u;
    int node = nodebase + tid;
    hl_s[tid] = node < N ? h_l[node] : 0.f;
  }
  if (tid < NET) he_s[tid] = he_tab[tid];
  for (int i = tid; i < NPB * 18; i += 256) accf[i] = 0.f;
  __syncthreads();
  for (int i = tid; i < m; i += 256)
    atomicAdd(&scnt[rec[(size_t)(s + i)] >> 20], 1u);
  __syncthreads();
  if (tid < NPB) {
    unsigned v = scnt[tid];
    unsigned orig = v;
    for (int off = 1; off < NPB; off <<= 1) {
      unsigned u = __shfl_up(v, off, 64);
      if (tid >= off) v += u;
    }
    soff[tid + 1] = v;
    scur[tid] = v - orig;
    if (tid == 0) soff[0] = 0u;
  }
  __syncthreads();
  for (int i = tid; i < m; i += 256) {
    unsigned r = rec[(size_t)(s + i)];
    unsigned pos = atomicAdd(&scur[r >> 20], 1u);
    srec[pos] = r;
  }
  // overflow fallback (cold; never taken for this input)
  for (int i = CAP + tid; i < cnt_all; i += 256) {
    unsigned r = rec[(size_t)(s + i)];
    int local = (int)(r >> 20);
    int typ = (int)((r >> 17) & 7u);
    int tl = (int)(r & 0x1FFFFu);
    float lg = hl_s[local] + h_r[tl] + he_s[typ];
    lg = lg > 0.f ? lg : 0.2f * lg;
    float ex = __expf(lg);
    const uint4* hp = (const uint4*)(ht + (size_t)tl * C_DIM);
    uint4 A = hp[0], B = hp[1];
    float* a = accf + local * 18;
    U2H cv;
    float2 f;
    unsigned wvv[8] = {A.x, A.y, A.z, A.w, B.x, B.y, B.z, B.w};
#pragma unroll
    for (int q = 0; q < 8; q++) {
      cv.u = wvv[q];
      f = __half22float2(cv.h);
      atomicAdd(a + 2 * q, ex * f.x);
      atomicAdd(a + 2 * q + 1, ex * f.y);
    }
    atomicAdd(a + 16, ex);
  }
  __syncthreads();
  int w = tid >> 6;
  int lane = tid & 63;
  int node_l = w * 16 + (lane >> 2);
  int p = lane & 3;
  float a[17];
#pragma unroll
  for (int k = 0; k < 17; k++) a[k] = 0.f;
  int st = (int)soff[node_l];
  int en = (int)soff[node_l + 1];
  float hlv = hl_s[node_l];
  for (int i = st + p; i < en; i += 4) {
    unsigned r = srec[i];
    int typ = (int)((r >> 17) & 7u);
    int tl = (int)(r & 0x1FFFFu);
    float lg = hlv + h_r[tl] + he_s[typ];
    lg = lg > 0.f ? lg : 0.2f * lg;
    float ex = __expf(lg);
    const uint4* hp = (const uint4*)(ht + (size_t)tl * C_DIM);
    uint4 A = hp[0], B = hp[1];
    U2H cv;
    float2 f;
    unsigned wd[8] = {A.x, A.y, A.z, A.w, B.x, B.y, B.z, B.w};
#pragma unroll
    for (int q = 0; q < 8; q++) {
      cv.u = wd[q];
      f = __half22float2(cv.h);
      a[2 * q] += ex * f.x;
      a[2 * q + 1] += ex * f.y;
    }
    a[16] += ex;
  }
#pragma unroll
  for (int k = 0; k < 17; k++) {
    a[k] += __shfl_xor(a[k], 1, 64);
    a[k] += __shfl_xor(a[k], 2, 64);
  }
  if (p != 0) return;
  int node = nodebase + node_l;
  if (node >= N) return;
  float d = a[16] + accf[node_l * 18 + 16];
  float inv = d > 0.f ? 1.f / d : 0.f;
  const f32x4* r4 = (const f32x4*)(resid + (size_t)node * C_DIM);
  float o[C_DIM];
  float ss = 0.f;
#pragma unroll
  for (int q = 0; q < 4; q++) {
    f32x4 rr = __builtin_nontemporal_load(r4 + q);
    o[4 * q + 0] =
        (a[4 * q + 0] + accf[node_l * 18 + 4 * q + 0]) * inv + rr.x + resb[4 * q + 0];
    o[4 * q + 1] =
        (a[4 * q + 1] + accf[node_l * 18 + 4 * q + 1]) * inv + rr.y + resb[4 * q + 1];
    o[4 * q + 2] =
        (a[4 * q + 2] + accf[node_l * 18 + 4 * q + 2]) * inv + rr.z + resb[4 * q + 2];
    o[4 * q + 3] =
        (a[4 * q + 3] + accf[node_l * 18 + 4 * q + 3]) * inv + rr.w + resb[4 * q + 3];
  }
#pragma unroll
  for (int cc = 0; cc < C_DIM; cc++) ss += o[cc] * o[cc];
  float sc = 1.f / fmaxf(sqrtf(ss), 1e-12f);
  float mx = -1e30f;
#pragma unroll
  for (int cc = 0; cc < C_DIM; cc++) {
    o[cc] *= sc;
    mx = fmaxf(mx, o[cc]);
  }
  float sum = 0.f;
#pragma unroll
  for (int cc = 0; cc < C_DIM; cc++) {
    o[cc] = __expf(o[cc] - mx);
    sum += o[cc];
  }
  float isum = 1.f / sum;
  f32x4* o4 = (f32x4*)(out + (size_t)node * C_DIM);
#pragma unroll
  for (int q = 0; q < 4; q++) {
    f32x4 ov;
    ov.x = o[4 * q] * isum;
    ov.y = o[4 * q + 1] * isum;
    ov.z = o[4 * q + 2] * isum;
    ov.w = o[4 * q + 3] * isum;
    __builtin_nontemporal_store(ov, o4 + q);
  }
}

// ---------------------------------------------------------------------------
extern "C" void kernel_launch(void* const* d_in, const int* in_sizes, int n_in,
                              void* d_out, int out_size, void* d_ws,
                              size_t ws_size, hipStream_t stream) {
  const float* head_feature = (const float*)d_in[0];
  const float* tail_feature = (const float*)d_in[1];
  const int* edge_index = (const int*)d_in[2];
  const int* tmp_edge = (const int*)d_in[3];
  const float* W = (const float*)d_in[4];
  const float* We = (const float*)d_in[5];
  const float* al = (const float*)d_in[6];
  const float* ar = (const float*)d_in[7];
  const float* ae = (const float*)d_in[8];
  const float* emb = (const float*)d_in[9];
  const float* resW = (const float*)d_in[10];
  const float* resb = (const float*)d_in[11];

  const int C = in_sizes[6];           // 16
  const int IN = in_sizes[4] / C;      // 512
  const int N = in_sizes[0] / IN;      // 100000
  const int E = in_sizes[3];           // 3200000
  const int EF = in_sizes[8];          // 64
  const int NET = in_sizes[9] / EF;    // 8
  const int NB = (N + NPB - 1) / NPB;  // 1563
  (void)C; (void)IN; (void)EF; (void)ws_size; (void)out_size; (void)n_in;

  const int* head = edge_index;
  const int* tail = edge_index + E;

  float* ws = (float*)d_ws;
  float* he = ws;                            // 32 f
  _Float16* Bph = (_Float16*)(he + 32);      // 8192 f16 (16KB)
  _Float16* Bpt = Bph + 8192;                // 8192 f16
  float* wlt = (float*)(Bpt + 8192);         // 512 f
  float* wrt = wlt + 512;                    // 512 f
  float* h_l = wrt + 512;                    // N
  float* h_r = h_l + N;                      // N
  __half* ht = (__half*)(h_r + N);           // 16N halves (32B rows, 3.2MB)
  float* resid = (float*)(ht + (size_t)C_DIM * N);  // 16N f32
  unsigned* rec = (unsigned*)(resid + (size_t)C_DIM * N);  // E u32 (4B rec)
  unsigned* cnt = rec + (size_t)E;           // SCB*CNTW
  unsigned* btotal = cnt + (size_t)SCB * CNTW;  // NBMAX2
  unsigned* bbase = btotal + NBMAX2;         // NBMAX2+1

  prep_kernel<<<1, 512, 0, stream>>>(W, We, al, ar, ae, emb, resW, he, Bph,
                                     Bpt, wlt, wrt, NET);
  dim3 pg((N + 63) / 64, 2);
  proj7_kernel<<<pg, 256, 0, stream>>>(head_feature, tail_feature, Bph, Bpt,
                                       wlt, wrt, resid, h_l, ht, h_r, N);

  int chunk = (E + SCB - 1) / SCB;
  hist_kernel<<<SCB, 512, 0, stream>>>(head, cnt, E, NB, chunk);
  colscan_kernel<<<(NB + 255) / 256, 256, 0, stream>>>(cnt, btotal, NB);
  scan_kernel<<<1, 1024, 0, stream>>>(btotal, bbase, NB);
  scatter_kernel<<<SCB, 512, 0, stream>>>(head, tail, tmp_edge, cnt, bbase,
                                          rec, E, NB, chunk);
  agg_kernel<<<NB, 256, 0, stream>>>(rec, bbase, ht, h_l, h_r, he, resid,
                                     resb, (float*)d_out, N, NET);
}